// Round 22
// baseline (41.694 us; speedup 1.0000x reference)
//
#include <hip/hip_runtime.h>
#include <hip/hip_bf16.h>
#include <cstdint>
#include <cstddef>

typedef __attribute__((ext_vector_type(8))) short bf16x8;
typedef __attribute__((ext_vector_type(4))) float f32x4;
typedef __attribute__((ext_vector_type(16))) float f32x16;
typedef __attribute__((ext_vector_type(2))) unsigned int u32x2;
typedef unsigned int u32;
typedef unsigned short u16;
typedef unsigned char u8;

__device__ __forceinline__ u16 f2bf(float f) {
  union { float f; u32 u; } v; v.f = f;
  u32 r = v.u + 0x7FFFu + ((v.u >> 16) & 1u);   // round-nearest-even
  return (u16)(r >> 16);
}
__device__ __forceinline__ u32 pk2(float a, float b) {
  return (u32)f2bf(a) | ((u32)f2bf(b) << 16);
}
__device__ __forceinline__ float bfhi(u32 u) {
  union { u32 u; float f; } v; v.u = u & 0xFFFF0000u; return v.f;
}
__device__ __forceinline__ float bflo(u32 u) {
  union { u32 u; float f; } v; v.u = u << 16; return v.f;
}
__device__ __forceinline__ float fexp2(float x) {
  return __builtin_amdgcn_exp2f(x);
}

// ---------------------------------------------------------------------------
// projection helper: one 16-row m-tile of Wcat(192x128) x LDS tile.
// q,k -> fp8 e4m3 scaled by sqrt(qscale*log2e)=0.3571 (so q'.k' = S in exp2
// domain directly); v -> fp8 K-major [b][n/32][128][32].
// ---------------------------------------------------------------------------
__device__ __forceinline__ void proj_tile(int mts, int li, int g,
    const u16* tb, int tb_stride_u16, int n0, int b,
    const float* Wq, const float* bq, const float* Wk, const float* bk,
    const float* Wv, const float* bv,
    u8* q8, u8* k8, u8* v2) {
  const float qks = 0.35709468f;    // sqrt(0.088388347648 * 1.442695041)
  int row = mts * 16 + li;
  const float* wsrc = row < 32 ? Wq + (size_t)row * 128
                    : row < 64 ? Wk + (size_t)(row - 32) * 128
                               : Wv + (size_t)(row - 64) * 128;
  int ob = mts * 16 + g * 4;
  const float* bsrc = ob < 32 ? bq + ob : ob < 64 ? bk + (ob - 32) : bv + (ob - 64);
  f32x4 acc[4];
#pragma unroll
  for (int nt = 0; nt < 4; ++nt) acc[nt] = (f32x4){0.f, 0.f, 0.f, 0.f};
#pragma unroll
  for (int kc = 0; kc < 4; ++kc) {
    float4 wa = *(const float4*)(wsrc + kc * 32 + g * 8);
    float4 wb = *(const float4*)(wsrc + kc * 32 + g * 8 + 4);
    union { u32 u[4]; bf16x8 v; } af;
    af.u[0] = pk2(wa.x, wa.y); af.u[1] = pk2(wa.z, wa.w);
    af.u[2] = pk2(wb.x, wb.y); af.u[3] = pk2(wb.z, wb.w);
    bf16x8 bfr[4];
#pragma unroll
    for (int nt = 0; nt < 4; ++nt)
      bfr[nt] = *(const bf16x8*)(tb + (size_t)(nt * 16 + li) * tb_stride_u16 + kc * 32 + g * 8);
#pragma unroll
    for (int nt = 0; nt < 4; ++nt)
      acc[nt] = __builtin_amdgcn_mfma_f32_16x16x32_bf16(af.v, bfr[nt], acc[nt], 0, 0, 0);
  }
  float bias[4];
#pragma unroll
  for (int r = 0; r < 4; ++r) bias[r] = bsrc[r];
#pragma unroll
  for (int nt = 0; nt < 4; ++nt) {
    int n = n0 + nt * 16 + li;
    float v0 = acc[nt][0] + bias[0];
    float v1 = acc[nt][1] + bias[1];
    float v2v = acc[nt][2] + bias[2];
    float v3 = acc[nt][3] + bias[3];
    if (mts < 4) {
      v0 *= qks; v1 *= qks; v2v *= qks; v3 *= qks;
      u32 w = (u32)__builtin_amdgcn_cvt_pk_fp8_f32(v0, v1, 0, false);
      w = (u32)__builtin_amdgcn_cvt_pk_fp8_f32(v2v, v3, (int)w, true);
      u8* dst = mts < 2 ? q8 : k8;
      int obb = mts < 2 ? ob : ob - 32;
      *(u32*)(dst + (((size_t)b * 4096) + n) * 32 + obb) = w;
    } else {
      int cv = ob - 64;
      u32 w01 = (u32)__builtin_amdgcn_cvt_pk_fp8_f32(v0, v1, 0, false);
      u32 w23 = (u32)__builtin_amdgcn_cvt_pk_fp8_f32(v2v, v3, 0, false);
      size_t vb = (((size_t)b * 128 + (n >> 5)) * 128 + cv) * 32 + (n & 31);
      v2[vb]      = (u8)(w01 & 0xFF);
      v2[vb + 32] = (u8)((w01 >> 8) & 0xFF);
      v2[vb + 64] = (u8)(w23 & 0xFF);
      v2[vb + 96] = (u8)((w23 >> 8) & 0xFF);
    }
  }
}

// ---------------------------------------------------------------------------
// Kernel 1 (fused prep + proj): bilinear PE (exact 2x-upsample taps);
// xp only in LDS; projection from LDS, weights straight from global f32.
// ---------------------------------------------------------------------------
__global__ __launch_bounds__(512) void k_pp(const float* __restrict__ x,
    const float* __restrict__ pos,
    const float* __restrict__ Wq, const float* __restrict__ bq,
    const float* __restrict__ Wk, const float* __restrict__ bk,
    const float* __restrict__ Wv, const float* __restrict__ bv,
    u8* __restrict__ q8, u8* __restrict__ k8, u8* __restrict__ v2) {
  __shared__ float tf[128][66];
  __shared__ u16 tb[64][136];
  int t = threadIdx.x;
  int n0 = blockIdx.x * 64;
  int b = blockIdx.y;
  int h = blockIdx.x;
  int hj = h >> 1;
  int ya, yb; float wa, wb;
  if ((h & 1) == 0) { ya = hj - 1 < 0 ? 0 : hj - 1; yb = hj; wa = 0.25f; wb = 0.75f; }
  else             { ya = hj; yb = hj + 1 > 31 ? 31 : hj + 1; wa = 0.75f; wb = 0.25f; }
  {
    int cl = t >> 2, q4 = t & 3;
    int w0 = q4 * 16;
    const float* pr0 = pos + (size_t)cl * 1024 + ya * 32;
    const float* pr1 = pos + (size_t)cl * 1024 + yb * 32;
    int i0 = q4 * 8;
    float rr[10];
#pragma unroll
    for (int j = 0; j < 10; ++j) {
      int idx = i0 - 1 + j;
      idx = idx < 0 ? 0 : (idx > 31 ? 31 : idx);
      rr[j] = wa * pr0[idx] + wb * pr1[idx];
    }
    size_t gbase = ((size_t)(b * 128 + cl)) * 4096 + h * 64 + w0;
#pragma unroll
    for (int u = 0; u < 4; ++u) {
      float4 xv = *(const float4*)(x + gbase + u * 4);
      float vals[4] = {xv.x, xv.y, xv.z, xv.w};
#pragma unroll
      for (int j = 0; j < 4; ++j) {
        int e = u * 4 + j;
        int li = (e >> 1) + 1;
        float pe = (e & 1) == 0 ? 0.25f * rr[li - 1] + 0.75f * rr[li]
                                : 0.75f * rr[li] + 0.25f * rr[li + 1];
        tf[cl][w0 + e] = vals[j] + 0.025f * pe;
      }
    }
  }
  __syncthreads();
  {
    int nl = t & 63, qr = t >> 6;
    u32* tbw = (u32*)&tb[0][0];
#pragma unroll
    for (int p = 0; p < 8; ++p)
      tbw[nl * 68 + qr * 8 + p] =
          pk2(tf[qr * 16 + 2 * p][nl], tf[qr * 16 + 2 * p + 1][nl]);
  }
  __syncthreads();
  int wv = t >> 6, lane = t & 63, li = lane & 15, g = lane >> 4;
  proj_tile(wv, li, g, &tb[0][0], 136, n0, b, Wq, bq, Wk, bk, Wv, bv, q8, k8, v2);
  if (wv < 4)
    proj_tile(8 + wv, li, g, &tb[0][0], 136, n0, b, Wq, bq, Wk, bk, Wv, bv, q8, k8, v2);
}

// ---------------------------------------------------------------------------
// Kernel 2: flash attention, ONE 32-row q-subtile per block (acc 64 VGPR ->
// 4 waves/SIMD, 2 blocks/CU) + XCD-affinity remap. Post-remap K/V re-reads
// are batch-local L2 hits, so doubling KV traffic (vs 64-row blocks) buys
// 2x occupancy/TLP. All-fp8, no online max, V top-load, K rotation.
// Grid 512 blocks (128 qtiles x 4 batches).
// ---------------------------------------------------------------------------
__global__ __launch_bounds__(512, 4) void k_attn(const u8* __restrict__ q8,
    const u8* __restrict__ k8, const u8* __restrict__ v2,
    const float* __restrict__ x, const float* __restrict__ pos,
    const float* __restrict__ gamma, float* __restrict__ out) {
  __shared__ u32 buf[4][32][66];    // bf16-pair partial O^T
  __shared__ float ll[8][32];
  int t = threadIdx.x;
  int wv = t >> 6, lane = t & 63;
  int q = lane & 31, hi = lane >> 5;
  // XCD-affinity remap (bijective on 512 blocks): 2 XCDs per batch
  int flat = blockIdx.x + 128 * blockIdx.y;
  int xcd = flat & 7;
  int b = xcd >> 1;
  int qt = (xcd & 1) * 64 + (flat >> 3);   // 0..127
  int q0 = qt * 32;
  const u8* qb8 = q8 + (((size_t)b * 4096) + q0) * 32;
  union { uint2 u; long long l_; } qAlo, qAhi;
  qAlo.u = *(const uint2*)(qb8 + (size_t)q * 32 + hi * 8);
  qAhi.u = *(const uint2*)(qb8 + (size_t)q * 32 + 16 + hi * 8);
  f32x16 accA[4] = {};
  const f32x16 zz = {};
  float sumA = 0.f;
  const u8* kbb = k8 + (size_t)b * 4096 * 32;
  const u8* vbb = v2 + (size_t)b * 524288;
  int kv_beg = wv * 512;
  union { uint2 u; long long l_; } kl, kh;
  kl.u = *(const uint2*)(kbb + (size_t)(kv_beg + q) * 32 + hi * 8);
  kh.u = *(const uint2*)(kbb + (size_t)(kv_beg + q) * 32 + 16 + hi * 8);

  for (int it = 0; it < 16; ++it) {
    int kv0 = kv_beg + it * 32;
    const u8* vch = vbb + (size_t)(kv0 >> 5) * 4096 + q * 32 + hi * 8;
    uint2 vr[8];
#pragma unroll
    for (int ct = 0; ct < 4; ++ct) {
      vr[2 * ct]     = *(const uint2*)(vch + ct * 1024);
      vr[2 * ct + 1] = *(const uint2*)(vch + ct * 1024 + 16);
    }
    f32x16 sA = __builtin_amdgcn_mfma_f32_32x32x16_fp8_fp8(kl.l_, qAlo.l_, zz, 0, 0, 0);
    sA = __builtin_amdgcn_mfma_f32_32x32x16_fp8_fp8(kh.l_, qAhi.l_, sA, 0, 0, 0);
    if (it < 15) {
      const u8* krn = kbb + (size_t)(kv0 + 32 + q) * 32 + hi * 8;
      kl.u = *(const uint2*)krn;
      kh.u = *(const uint2*)(krn + 16);
    }
    {
      float p[16];
#pragma unroll
      for (int r = 0; r < 16; ++r) p[r] = fexp2(sA[r]);
      float s0 = (p[0] + p[1]) + (p[2] + p[3]);
      float s1 = (p[4] + p[5]) + (p[6] + p[7]);
      float s2 = (p[8] + p[9]) + (p[10] + p[11]);
      float s3 = (p[12] + p[13]) + (p[14] + p[15]);
      sumA += (s0 + s1) + (s2 + s3);
      u32 dw0 = (u32)__builtin_amdgcn_cvt_pk_fp8_f32(p[0], p[1], 0, false);
      dw0 = (u32)__builtin_amdgcn_cvt_pk_fp8_f32(p[2], p[3], (int)dw0, true);
      u32 dw1 = (u32)__builtin_amdgcn_cvt_pk_fp8_f32(p[4], p[5], 0, false);
      dw1 = (u32)__builtin_amdgcn_cvt_pk_fp8_f32(p[6], p[7], (int)dw1, true);
      u32 dw2 = (u32)__builtin_amdgcn_cvt_pk_fp8_f32(p[8], p[9], 0, false);
      dw2 = (u32)__builtin_amdgcn_cvt_pk_fp8_f32(p[10], p[11], (int)dw2, true);
      u32 dw3 = (u32)__builtin_amdgcn_cvt_pk_fp8_f32(p[12], p[13], 0, false);
      dw3 = (u32)__builtin_amdgcn_cvt_pk_fp8_f32(p[14], p[15], (int)dw3, true);
      u32x2 sw0 = __builtin_amdgcn_permlane32_swap(dw0, dw1, false, false);
      u32x2 sw1 = __builtin_amdgcn_permlane32_swap(dw2, dw3, false, false);
      union { uint2 u; long long l_; } pf0, pf1;
      pf0.u.x = sw0[0]; pf0.u.y = sw0[1];
      pf1.u.x = sw1[0]; pf1.u.y = sw1[1];
#pragma unroll
      for (int ct = 0; ct < 4; ++ct) {
        union { uint2 u; long long l_; } v0u, v1u;
        v0u.u = vr[2 * ct]; v1u.u = vr[2 * ct + 1];
        accA[ct] = __builtin_amdgcn_mfma_f32_32x32x16_fp8_fp8(v0u.l_, pf0.l_, accA[ct], 0, 0, 0);
        accA[ct] = __builtin_amdgcn_mfma_f32_32x32x16_fp8_fp8(v1u.l_, pf1.l_, accA[ct], 0, 0, 0);
      }
    }
  }

  // combine lane halves of l partial
  float lA;
  {
    union { float f; u32 u; } cv; cv.f = sumA;
    u32x2 sw = __builtin_amdgcn_permlane32_swap(cv.u, cv.u, false, false);
    union { u32 u; float f; } r0, r1; r0.u = sw[0]; r1.u = sw[1];
    lA = r0.f + r1.f;
  }

  float g0 = gamma[0];
  // ---- combine: 8 -> 4 partial-add, then 4-way epilogue ----
  __syncthreads();
  if (lane < 32) ll[wv][q] = lA;
  if (wv >= 4) {
    int w = wv - 4;
#pragma unroll
    for (int ct = 0; ct < 4; ++ct)
#pragma unroll
      for (int q4 = 0; q4 < 4; ++q4) {
        uint2 pkd;
        pkd.x = pk2(accA[ct][q4 * 4 + 0], accA[ct][q4 * 4 + 1]);
        pkd.y = pk2(accA[ct][q4 * 4 + 2], accA[ct][q4 * 4 + 3]);
        *(uint2*)&buf[w][q][16 * ct + 4 * q4 + 2 * hi] = pkd;
      }
  }
  __syncthreads();
  if (wv < 4) {
    float lv2 = ll[wv + 4][q];
#pragma unroll
    for (int ct = 0; ct < 4; ++ct)
#pragma unroll
      for (int q4 = 0; q4 < 4; ++q4) {
        uint2 pr = *(const uint2*)&buf[wv][q][16 * ct + 4 * q4 + 2 * hi];
        accA[ct][q4 * 4 + 0] += bflo(pr.x);
        accA[ct][q4 * 4 + 1] += bfhi(pr.x);
        accA[ct][q4 * 4 + 2] += bflo(pr.y);
        accA[ct][q4 * 4 + 3] += bfhi(pr.y);
      }
#pragma unroll
    for (int ct = 0; ct < 4; ++ct)
#pragma unroll
      for (int q4 = 0; q4 < 4; ++q4) {
        uint2 pkd;
        pkd.x = pk2(accA[ct][q4 * 4 + 0], accA[ct][q4 * 4 + 1]);
        pkd.y = pk2(accA[ct][q4 * 4 + 2], accA[ct][q4 * 4 + 3]);
        *(uint2*)&buf[wv][q][16 * ct + 4 * q4 + 2 * hi] = pkd;
      }
    if (lane < 32) ll[wv][q] = lA + lv2;
  }
  __syncthreads();
  {
    int qe = t & 31, cgr = t >> 5;
    float ls = ll[0][qe] + ll[1][qe] + ll[2][qe] + ll[3][qe];
    float inv = 1.f / ls;
    float sacc[8];
#pragma unroll
    for (int j = 0; j < 8; ++j) sacc[j] = 0.f;
#pragma unroll
    for (int w = 0; w < 4; ++w) {
      uint4 r = *(const uint4*)&buf[w][qe][cgr * 4];
      sacc[0] += bflo(r.x); sacc[1] += bfhi(r.x);
      sacc[2] += bflo(r.y); sacc[3] += bfhi(r.y);
      sacc[4] += bflo(r.z); sacc[5] += bfhi(r.z);
      sacc[6] += bflo(r.w); sacc[7] += bfhi(r.w);
    }
    // PE taps: block covers n = qt*32 .. qt*32+31 -> h = qt>>1 (uniform),
    // w = (qt&1)*32 + qe
    int hh = qt >> 1;
    int hj2 = hh >> 1;
    int ya2, ybI; float wya, wyb;
    if ((hh & 1) == 0) { ya2 = hj2 - 1 < 0 ? 0 : hj2 - 1; ybI = hj2;
                         wya = 0.25f; wyb = 0.75f; }
    else               { ya2 = hj2; ybI = hj2 + 1 > 31 ? 31 : hj2 + 1;
                         wya = 0.75f; wyb = 0.25f; }
    int ww = (qt & 1) * 32 + qe;
    int wj = ww >> 1;
    int xaI, xbI; float wxa, wxb;
    if ((ww & 1) == 0) { xaI = wj - 1 < 0 ? 0 : wj - 1; xbI = wj;
                         wxa = 0.25f; wxb = 0.75f; }
    else               { xaI = wj; xbI = wj + 1 > 31 ? 31 : wj + 1;
                         wxa = 0.75f; wxb = 0.25f; }
    int o00 = ya2 * 32 + xaI, o01 = ya2 * 32 + xbI;
    int o10 = ybI * 32 + xaI, o11 = ybI * 32 + xbI;
#pragma unroll
    for (int j = 0; j < 8; ++j) {
      int c = cgr * 8 + j;
      const float* pj = pos + (size_t)c * 1024;
      float pe = wya * (wxa * pj[o00] + wxb * pj[o01])
               + wyb * (wxa * pj[o10] + wxb * pj[o11]);
      size_t adr = (((size_t)b * 128) + c) * 4096 + q0 + qe;
      out[adr] = g0 * sacc[j] * inv + x[adr] + 0.025f * pe;
    }
  }
}

// ---------------------------------------------------------------------------
extern "C" void kernel_launch(void* const* d_in, const int* in_sizes, int n_in,
                              void* d_out, int out_size, void* d_ws, size_t ws_size,
                              hipStream_t stream) {
  const float* x     = (const float*)d_in[0];
  const float* Wq    = (const float*)d_in[1];
  const float* bq    = (const float*)d_in[2];
  const float* Wk    = (const float*)d_in[3];
  const float* bk    = (const float*)d_in[4];
  const float* Wv    = (const float*)d_in[5];
  const float* bv    = (const float*)d_in[6];
  const float* gamma = (const float*)d_in[7];
  const float* pos   = (const float*)d_in[8];
  float* out = (float*)d_out;

  char* ws = (char*)d_ws;
  u8* q8 = (u8*)ws;                       //   524,288 B  fp8 [4][4096][32]
  u8* k8 = (u8*)(ws + 524288);            //   524,288 B  fp8 [4][4096][32]
  u8* v2 = (u8*)(ws + 1048576);           // 2,097,152 B  fp8 [4][128][128][32]

  k_pp<<<dim3(64, 4), 512, 0, stream>>>(x, pos, Wq, bq, Wk, bk, Wv, bv,
                                        q8, k8, v2);
  k_attn<<<dim3(128, 4), 512, 0, stream>>>(q8, k8, v2, x, pos, gamma, out);
}

// Round 23
// 36.910 us; speedup vs baseline: 1.1296x; 1.1296x over previous
//
#include <hip/hip_runtime.h>
#include <hip/hip_bf16.h>
#include <cstdint>
#include <cstddef>

typedef __attribute__((ext_vector_type(8))) short bf16x8;
typedef __attribute__((ext_vector_type(4))) float f32x4;
typedef __attribute__((ext_vector_type(16))) float f32x16;
typedef __attribute__((ext_vector_type(2))) unsigned int u32x2;
typedef unsigned int u32;
typedef unsigned short u16;
typedef unsigned char u8;

__device__ __forceinline__ u16 f2bf(float f) {
  union { float f; u32 u; } v; v.f = f;
  u32 r = v.u + 0x7FFFu + ((v.u >> 16) & 1u);   // round-nearest-even
  return (u16)(r >> 16);
}
__device__ __forceinline__ u32 pk2(float a, float b) {
  return (u32)f2bf(a) | ((u32)f2bf(b) << 16);
}
__device__ __forceinline__ float bfhi(u32 u) {
  union { u32 u; float f; } v; v.u = u & 0xFFFF0000u; return v.f;
}
__device__ __forceinline__ float bflo(u32 u) {
  union { u32 u; float f; } v; v.u = u << 16; return v.f;
}
__device__ __forceinline__ float fexp2(float x) {
  return __builtin_amdgcn_exp2f(x);
}

// ---------------------------------------------------------------------------
// projection helper: one 16-row m-tile of Wcat(192x128) x LDS tile.
// q,k -> fp8 e4m3 scaled by sqrt(qscale*log2e)=0.3571 (so q'.k' = S in exp2
// domain directly); v -> fp8 K-major [b][n/32][128][32].
// ---------------------------------------------------------------------------
__device__ __forceinline__ void proj_tile(int mts, int li, int g,
    const u16* tb, int tb_stride_u16, int n0, int b,
    const float* Wq, const float* bq, const float* Wk, const float* bk,
    const float* Wv, const float* bv,
    u8* q8, u8* k8, u8* v2) {
  const float qks = 0.35709468f;    // sqrt(0.088388347648 * 1.442695041)
  int row = mts * 16 + li;
  const float* wsrc = row < 32 ? Wq + (size_t)row * 128
                    : row < 64 ? Wk + (size_t)(row - 32) * 128
                               : Wv + (size_t)(row - 64) * 128;
  int ob = mts * 16 + g * 4;
  const float* bsrc = ob < 32 ? bq + ob : ob < 64 ? bk + (ob - 32) : bv + (ob - 64);
  f32x4 acc[4];
#pragma unroll
  for (int nt = 0; nt < 4; ++nt) acc[nt] = (f32x4){0.f, 0.f, 0.f, 0.f};
#pragma unroll
  for (int kc = 0; kc < 4; ++kc) {
    float4 wa = *(const float4*)(wsrc + kc * 32 + g * 8);
    float4 wb = *(const float4*)(wsrc + kc * 32 + g * 8 + 4);
    union { u32 u[4]; bf16x8 v; } af;
    af.u[0] = pk2(wa.x, wa.y); af.u[1] = pk2(wa.z, wa.w);
    af.u[2] = pk2(wb.x, wb.y); af.u[3] = pk2(wb.z, wb.w);
    bf16x8 bfr[4];
#pragma unroll
    for (int nt = 0; nt < 4; ++nt)
      bfr[nt] = *(const bf16x8*)(tb + (size_t)(nt * 16 + li) * tb_stride_u16 + kc * 32 + g * 8);
#pragma unroll
    for (int nt = 0; nt < 4; ++nt)
      acc[nt] = __builtin_amdgcn_mfma_f32_16x16x32_bf16(af.v, bfr[nt], acc[nt], 0, 0, 0);
  }
  float bias[4];
#pragma unroll
  for (int r = 0; r < 4; ++r) bias[r] = bsrc[r];
#pragma unroll
  for (int nt = 0; nt < 4; ++nt) {
    int n = n0 + nt * 16 + li;
    float v0 = acc[nt][0] + bias[0];
    float v1 = acc[nt][1] + bias[1];
    float v2v = acc[nt][2] + bias[2];
    float v3 = acc[nt][3] + bias[3];
    if (mts < 4) {
      v0 *= qks; v1 *= qks; v2v *= qks; v3 *= qks;
      u32 w = (u32)__builtin_amdgcn_cvt_pk_fp8_f32(v0, v1, 0, false);
      w = (u32)__builtin_amdgcn_cvt_pk_fp8_f32(v2v, v3, (int)w, true);
      u8* dst = mts < 2 ? q8 : k8;
      int obb = mts < 2 ? ob : ob - 32;
      *(u32*)(dst + (((size_t)b * 4096) + n) * 32 + obb) = w;
    } else {
      int cv = ob - 64;
      u32 w01 = (u32)__builtin_amdgcn_cvt_pk_fp8_f32(v0, v1, 0, false);
      u32 w23 = (u32)__builtin_amdgcn_cvt_pk_fp8_f32(v2v, v3, 0, false);
      size_t vb = (((size_t)b * 128 + (n >> 5)) * 128 + cv) * 32 + (n & 31);
      v2[vb]      = (u8)(w01 & 0xFF);
      v2[vb + 32] = (u8)((w01 >> 8) & 0xFF);
      v2[vb + 64] = (u8)(w23 & 0xFF);
      v2[vb + 96] = (u8)((w23 >> 8) & 0xFF);
    }
  }
}

// ---------------------------------------------------------------------------
// Kernel 1 (fused prep + proj): bilinear PE (exact 2x-upsample taps);
// xp only in LDS; projection from LDS, weights straight from global f32.
// ---------------------------------------------------------------------------
__global__ __launch_bounds__(512) void k_pp(const float* __restrict__ x,
    const float* __restrict__ pos,
    const float* __restrict__ Wq, const float* __restrict__ bq,
    const float* __restrict__ Wk, const float* __restrict__ bk,
    const float* __restrict__ Wv, const float* __restrict__ bv,
    u8* __restrict__ q8, u8* __restrict__ k8, u8* __restrict__ v2) {
  __shared__ float tf[128][66];
  __shared__ u16 tb[64][136];
  int t = threadIdx.x;
  int n0 = blockIdx.x * 64;
  int b = blockIdx.y;
  int h = blockIdx.x;
  int hj = h >> 1;
  int ya, yb; float wa, wb;
  if ((h & 1) == 0) { ya = hj - 1 < 0 ? 0 : hj - 1; yb = hj; wa = 0.25f; wb = 0.75f; }
  else             { ya = hj; yb = hj + 1 > 31 ? 31 : hj + 1; wa = 0.75f; wb = 0.25f; }
  {
    int cl = t >> 2, q4 = t & 3;
    int w0 = q4 * 16;
    const float* pr0 = pos + (size_t)cl * 1024 + ya * 32;
    const float* pr1 = pos + (size_t)cl * 1024 + yb * 32;
    int i0 = q4 * 8;
    float rr[10];
#pragma unroll
    for (int j = 0; j < 10; ++j) {
      int idx = i0 - 1 + j;
      idx = idx < 0 ? 0 : (idx > 31 ? 31 : idx);
      rr[j] = wa * pr0[idx] + wb * pr1[idx];
    }
    size_t gbase = ((size_t)(b * 128 + cl)) * 4096 + h * 64 + w0;
#pragma unroll
    for (int u = 0; u < 4; ++u) {
      float4 xv = *(const float4*)(x + gbase + u * 4);
      float vals[4] = {xv.x, xv.y, xv.z, xv.w};
#pragma unroll
      for (int j = 0; j < 4; ++j) {
        int e = u * 4 + j;
        int li = (e >> 1) + 1;
        float pe = (e & 1) == 0 ? 0.25f * rr[li - 1] + 0.75f * rr[li]
                                : 0.75f * rr[li] + 0.25f * rr[li + 1];
        tf[cl][w0 + e] = vals[j] + 0.025f * pe;
      }
    }
  }
  __syncthreads();
  {
    int nl = t & 63, qr = t >> 6;
    u32* tbw = (u32*)&tb[0][0];
#pragma unroll
    for (int p = 0; p < 8; ++p)
      tbw[nl * 68 + qr * 8 + p] =
          pk2(tf[qr * 16 + 2 * p][nl], tf[qr * 16 + 2 * p + 1][nl]);
  }
  __syncthreads();
  int wv = t >> 6, lane = t & 63, li = lane & 15, g = lane >> 4;
  proj_tile(wv, li, g, &tb[0][0], 136, n0, b, Wq, bq, Wk, bk, Wv, bv, q8, k8, v2);
  if (wv < 4)
    proj_tile(8 + wv, li, g, &tb[0][0], 136, n0, b, Wq, bq, Wk, bk, Wv, bv, q8, k8, v2);
}

// ---------------------------------------------------------------------------
// Kernel 2: flash attention (round-16 schedule) + XCD-affinity block remap:
// flat = bx + 64*by dispatches round-robin over 8 XCDs (xcd = flat&7), so
// remapping batch = (flat&7)>>1 pins each batch's 64 blocks to a dedicated
// XCD pair -> per-XCD L2 KV working set drops 2.56 MB -> 640 KB and KV lines
// are no longer replicated into all 8 L2s (T1 mechanism at batch granularity).
// All-fp8 (q,K,V e4m3), no online max, V top-load, K rotation.
// ---------------------------------------------------------------------------
__global__ __launch_bounds__(512, 2) void k_attn(const u8* __restrict__ q8,
    const u8* __restrict__ k8, const u8* __restrict__ v2,
    const float* __restrict__ x, const float* __restrict__ pos,
    const float* __restrict__ gamma, float* __restrict__ out) {
  __shared__ u32 buf[4][32][66];    // bf16-pair partial O^T
  __shared__ float ll[8][32];
  int t = threadIdx.x;
  int wv = t >> 6, lane = t & 63;
  int q = lane & 31, hi = lane >> 5;
  // XCD-affinity remap (bijective on 256 blocks)
  int flat = blockIdx.x + 64 * blockIdx.y;
  int xcd = flat & 7;
  int b = xcd >> 1;                        // batch: 2 XCDs per batch
  int qt = (xcd & 1) * 32 + (flat >> 3);   // q-tile 0..63
  int q0 = qt * 64;
  const u8* qb8 = q8 + (((size_t)b * 4096) + q0) * 32;
  union { uint2 u; long long l_; } qAlo, qAhi, qBlo, qBhi;
  qAlo.u = *(const uint2*)(qb8 + (size_t)q * 32 + hi * 8);
  qAhi.u = *(const uint2*)(qb8 + (size_t)q * 32 + 16 + hi * 8);
  qBlo.u = *(const uint2*)(qb8 + (size_t)(32 + q) * 32 + hi * 8);
  qBhi.u = *(const uint2*)(qb8 + (size_t)(32 + q) * 32 + 16 + hi * 8);
  f32x16 accA[4] = {}, accB[4] = {};
  const f32x16 zz = {};
  float sumA = 0.f, sumB = 0.f;    // lane-local l partials
  const u8* kbb = k8 + (size_t)b * 4096 * 32;
  const u8* vbb = v2 + (size_t)b * 524288;
  int kv_beg = wv * 512;
  union { uint2 u; long long l_; } kl, kh;
  kl.u = *(const uint2*)(kbb + (size_t)(kv_beg + q) * 32 + hi * 8);
  kh.u = *(const uint2*)(kbb + (size_t)(kv_beg + q) * 32 + 16 + hi * 8);

  for (int it = 0; it < 16; ++it) {
    int kv0 = kv_beg + it * 32;
    const u8* vch = vbb + (size_t)(kv0 >> 5) * 4096 + q * 32 + hi * 8;
    uint2 vr[8];
#pragma unroll
    for (int ct = 0; ct < 4; ++ct) {
      vr[2 * ct]     = *(const uint2*)(vch + ct * 1024);
      vr[2 * ct + 1] = *(const uint2*)(vch + ct * 1024 + 16);
    }
    // QK^T fp8: S = K' . q'  (scale folded into both operands)
    f32x16 sA = __builtin_amdgcn_mfma_f32_32x32x16_fp8_fp8(kl.l_, qAlo.l_, zz, 0, 0, 0);
    sA = __builtin_amdgcn_mfma_f32_32x32x16_fp8_fp8(kh.l_, qAhi.l_, sA, 0, 0, 0);
    f32x16 sB = __builtin_amdgcn_mfma_f32_32x32x16_fp8_fp8(kl.l_, qBlo.l_, zz, 0, 0, 0);
    sB = __builtin_amdgcn_mfma_f32_32x32x16_fp8_fp8(kh.l_, qBhi.l_, sB, 0, 0, 0);
    // rotate K (completes during softmax+PV)
    if (it < 15) {
      const u8* krn = kbb + (size_t)(kv0 + 32 + q) * 32 + hi * 8;
      kl.u = *(const uint2*)krn;
      kh.u = *(const uint2*)(krn + 16);
    }
    // ---- subtile A: P = exp2(S), pack, PV ----
    {
      float p[16];
#pragma unroll
      for (int r = 0; r < 16; ++r) p[r] = fexp2(sA[r]);
      float s0 = (p[0] + p[1]) + (p[2] + p[3]);
      float s1 = (p[4] + p[5]) + (p[6] + p[7]);
      float s2 = (p[8] + p[9]) + (p[10] + p[11]);
      float s3 = (p[12] + p[13]) + (p[14] + p[15]);
      sumA += (s0 + s1) + (s2 + s3);
      u32 dw0 = (u32)__builtin_amdgcn_cvt_pk_fp8_f32(p[0], p[1], 0, false);
      dw0 = (u32)__builtin_amdgcn_cvt_pk_fp8_f32(p[2], p[3], (int)dw0, true);
      u32 dw1 = (u32)__builtin_amdgcn_cvt_pk_fp8_f32(p[4], p[5], 0, false);
      dw1 = (u32)__builtin_amdgcn_cvt_pk_fp8_f32(p[6], p[7], (int)dw1, true);
      u32 dw2 = (u32)__builtin_amdgcn_cvt_pk_fp8_f32(p[8], p[9], 0, false);
      dw2 = (u32)__builtin_amdgcn_cvt_pk_fp8_f32(p[10], p[11], (int)dw2, true);
      u32 dw3 = (u32)__builtin_amdgcn_cvt_pk_fp8_f32(p[12], p[13], 0, false);
      dw3 = (u32)__builtin_amdgcn_cvt_pk_fp8_f32(p[14], p[15], (int)dw3, true);
      u32x2 sw0 = __builtin_amdgcn_permlane32_swap(dw0, dw1, false, false);
      u32x2 sw1 = __builtin_amdgcn_permlane32_swap(dw2, dw3, false, false);
      union { uint2 u; long long l_; } pf0, pf1;
      pf0.u.x = sw0[0]; pf0.u.y = sw0[1];
      pf1.u.x = sw1[0]; pf1.u.y = sw1[1];
#pragma unroll
      for (int ct = 0; ct < 4; ++ct) {
        union { uint2 u; long long l_; } v0u, v1u;
        v0u.u = vr[2 * ct]; v1u.u = vr[2 * ct + 1];
        accA[ct] = __builtin_amdgcn_mfma_f32_32x32x16_fp8_fp8(v0u.l_, pf0.l_, accA[ct], 0, 0, 0);
        accA[ct] = __builtin_amdgcn_mfma_f32_32x32x16_fp8_fp8(v1u.l_, pf1.l_, accA[ct], 0, 0, 0);
      }
    }
    // ---- subtile B ----
    {
      float p[16];
#pragma unroll
      for (int r = 0; r < 16; ++r) p[r] = fexp2(sB[r]);
      float s0 = (p[0] + p[1]) + (p[2] + p[3]);
      float s1 = (p[4] + p[5]) + (p[6] + p[7]);
      float s2 = (p[8] + p[9]) + (p[10] + p[11]);
      float s3 = (p[12] + p[13]) + (p[14] + p[15]);
      sumB += (s0 + s1) + (s2 + s3);
      u32 dw0 = (u32)__builtin_amdgcn_cvt_pk_fp8_f32(p[0], p[1], 0, false);
      dw0 = (u32)__builtin_amdgcn_cvt_pk_fp8_f32(p[2], p[3], (int)dw0, true);
      u32 dw1 = (u32)__builtin_amdgcn_cvt_pk_fp8_f32(p[4], p[5], 0, false);
      dw1 = (u32)__builtin_amdgcn_cvt_pk_fp8_f32(p[6], p[7], (int)dw1, true);
      u32 dw2 = (u32)__builtin_amdgcn_cvt_pk_fp8_f32(p[8], p[9], 0, false);
      dw2 = (u32)__builtin_amdgcn_cvt_pk_fp8_f32(p[10], p[11], (int)dw2, true);
      u32 dw3 = (u32)__builtin_amdgcn_cvt_pk_fp8_f32(p[12], p[13], 0, false);
      dw3 = (u32)__builtin_amdgcn_cvt_pk_fp8_f32(p[14], p[15], (int)dw3, true);
      u32x2 sw0 = __builtin_amdgcn_permlane32_swap(dw0, dw1, false, false);
      u32x2 sw1 = __builtin_amdgcn_permlane32_swap(dw2, dw3, false, false);
      union { uint2 u; long long l_; } pf0, pf1;
      pf0.u.x = sw0[0]; pf0.u.y = sw0[1];
      pf1.u.x = sw1[0]; pf1.u.y = sw1[1];
#pragma unroll
      for (int ct = 0; ct < 4; ++ct) {
        union { uint2 u; long long l_; } v0u, v1u;
        v0u.u = vr[2 * ct]; v1u.u = vr[2 * ct + 1];
        accB[ct] = __builtin_amdgcn_mfma_f32_32x32x16_fp8_fp8(v0u.l_, pf0.l_, accB[ct], 0, 0, 0);
        accB[ct] = __builtin_amdgcn_mfma_f32_32x32x16_fp8_fp8(v1u.l_, pf1.l_, accB[ct], 0, 0, 0);
      }
    }
  }

  // combine lane halves of l partials
  float lA, lB;
  {
    union { float f; u32 u; } cv; cv.f = sumA;
    u32x2 sw = __builtin_amdgcn_permlane32_swap(cv.u, cv.u, false, false);
    union { u32 u; float f; } r0, r1; r0.u = sw[0]; r1.u = sw[1];
    lA = r0.f + r1.f;
    cv.f = sumB;
    sw = __builtin_amdgcn_permlane32_swap(cv.u, cv.u, false, false);
    r0.u = sw[0]; r1.u = sw[1];
    lB = r0.f + r1.f;
  }

  float g0 = gamma[0];
#define COMBINE_PASS(ACC, LV, QOFF)                                           \
  __syncthreads();                                                            \
  if (lane < 32) ll[wv][q] = LV;                                              \
  if (wv >= 4) {                                                              \
    int w = wv - 4;                                                           \
    _Pragma("unroll")                                                         \
    for (int ct = 0; ct < 4; ++ct)                                            \
      _Pragma("unroll")                                                       \
      for (int q4 = 0; q4 < 4; ++q4) {                                        \
        uint2 pkd;                                                            \
        pkd.x = pk2(ACC[ct][q4 * 4 + 0], ACC[ct][q4 * 4 + 1]);                \
        pkd.y = pk2(ACC[ct][q4 * 4 + 2], ACC[ct][q4 * 4 + 3]);                \
        *(uint2*)&buf[w][q][16 * ct + 4 * q4 + 2 * hi] = pkd;                 \
      }                                                                       \
  }                                                                           \
  __syncthreads();                                                            \
  if (wv < 4) {                                                               \
    float lv2 = ll[wv + 4][q];                                                \
    _Pragma("unroll")                                                         \
    for (int ct = 0; ct < 4; ++ct)                                            \
      _Pragma("unroll")                                                       \
      for (int q4 = 0; q4 < 4; ++q4) {                                        \
        uint2 pr = *(const uint2*)&buf[wv][q][16 * ct + 4 * q4 + 2 * hi];     \
        ACC[ct][q4 * 4 + 0] += bflo(pr.x);                                    \
        ACC[ct][q4 * 4 + 1] += bfhi(pr.x);                                    \
        ACC[ct][q4 * 4 + 2] += bflo(pr.y);                                    \
        ACC[ct][q4 * 4 + 3] += bfhi(pr.y);                                    \
      }                                                                       \
    _Pragma("unroll")                                                         \
    for (int ct = 0; ct < 4; ++ct)                                            \
      _Pragma("unroll")                                                       \
      for (int q4 = 0; q4 < 4; ++q4) {                                        \
        uint2 pkd;                                                            \
        pkd.x = pk2(ACC[ct][q4 * 4 + 0], ACC[ct][q4 * 4 + 1]);                \
        pkd.y = pk2(ACC[ct][q4 * 4 + 2], ACC[ct][q4 * 4 + 3]);                \
        *(uint2*)&buf[wv][q][16 * ct + 4 * q4 + 2 * hi] = pkd;                \
      }                                                                       \
    if (lane < 32) ll[wv][q] = LV + lv2;                                      \
  }                                                                           \
  __syncthreads();                                                            \
  {                                                                           \
    int qe = t & 31, cgr = t >> 5;                                            \
    float ls = ll[0][qe] + ll[1][qe] + ll[2][qe] + ll[3][qe];                 \
    float inv = 1.f / ls;                                                     \
    float sacc[8];                                                            \
    _Pragma("unroll")                                                         \
    for (int j = 0; j < 8; ++j) sacc[j] = 0.f;                                \
    _Pragma("unroll")                                                         \
    for (int w = 0; w < 4; ++w) {                                             \
      uint4 r = *(const uint4*)&buf[w][qe][cgr * 4];                          \
      sacc[0] += bflo(r.x); sacc[1] += bfhi(r.x);                             \
      sacc[2] += bflo(r.y); sacc[3] += bfhi(r.y);                             \
      sacc[4] += bflo(r.z); sacc[5] += bfhi(r.z);                             \
      sacc[6] += bflo(r.w); sacc[7] += bfhi(r.w);                             \
    }                                                                         \
    int hh = qt;                                                              \
    int hj2 = hh >> 1;                                                        \
    int ya2, ybI; float wya, wyb;                                             \
    if ((hh & 1) == 0) { ya2 = hj2 - 1 < 0 ? 0 : hj2 - 1; ybI = hj2;          \
                         wya = 0.25f; wyb = 0.75f; }                          \
    else               { ya2 = hj2; ybI = hj2 + 1 > 31 ? 31 : hj2 + 1;        \
                         wya = 0.75f; wyb = 0.25f; }                          \
    int ww = (QOFF) + qe;                                                     \
    int wj = ww >> 1;                                                         \
    int xaI, xbI; float wxa, wxb;                                             \
    if ((ww & 1) == 0) { xaI = wj - 1 < 0 ? 0 : wj - 1; xbI = wj;             \
                         wxa = 0.25f; wxb = 0.75f; }                          \
    else               { xaI = wj; xbI = wj + 1 > 31 ? 31 : wj + 1;           \
                         wxa = 0.75f; wxb = 0.25f; }                          \
    int o00 = ya2 * 32 + xaI, o01 = ya2 * 32 + xbI;                           \
    int o10 = ybI * 32 + xaI, o11 = ybI * 32 + xbI;                           \
    _Pragma("unroll")                                                         \
    for (int j = 0; j < 8; ++j) {                                             \
      int c = cgr * 8 + j;                                                    \
      const float* pj = pos + (size_t)c * 1024;                               \
      float pe = wya * (wxa * pj[o00] + wxb * pj[o01])                        \
               + wyb * (wxa * pj[o10] + wxb * pj[o11]);                       \
      size_t adr = (((size_t)b * 128) + c) * 4096 + q0 + (QOFF) + qe;         \
      out[adr] = g0 * sacc[j] * inv + x[adr] + 0.025f * pe;                   \
    }                                                                         \
  }

  COMBINE_PASS(accA, lA, 0)
  COMBINE_PASS(accB, lB, 32)
#undef COMBINE_PASS
}

// ---------------------------------------------------------------------------
extern "C" void kernel_launch(void* const* d_in, const int* in_sizes, int n_in,
                              void* d_out, int out_size, void* d_ws, size_t ws_size,
                              hipStream_t stream) {
  const float* x     = (const float*)d_in[0];
  const float* Wq    = (const float*)d_in[1];
  const float* bq    = (const float*)d_in[2];
  const float* Wk    = (const float*)d_in[3];
  const float* bk    = (const float*)d_in[4];
  const float* Wv    = (const float*)d_in[5];
  const float* bv    = (const float*)d_in[6];
  const float* gamma = (const float*)d_in[7];
  const float* pos   = (const float*)d_in[8];
  float* out = (float*)d_out;

  char* ws = (char*)d_ws;
  u8* q8 = (u8*)ws;                       //   524,288 B  fp8 [4][4096][32]
  u8* k8 = (u8*)(ws + 524288);            //   524,288 B  fp8 [4][4096][32]
  u8* v2 = (u8*)(ws + 1048576);           // 2,097,152 B  fp8 [4][128][128][32]

  k_pp<<<dim3(64, 4), 512, 0, stream>>>(x, pos, Wq, bq, Wk, bk, Wv, bv,
                                        q8, k8, v2);
  k_attn<<<dim3(64, 4), 512, 0, stream>>>(q8, k8, v2, x, pos, gamma, out);
}